// Round 16
// baseline (1295.611 us; speedup 1.0000x reference)
//
#include <hip/hip_runtime.h>
#include <hip/hip_bf16.h>

// PointConv SetAbstraction for MI355X. B=8,N=4096,S=1024,K=32,D=64.
#define BB 8
#define NN 4096
#define SS 1024
#define KK 32
#define PP (BB*SS*KK)   // 262144

typedef unsigned long long u64;
typedef unsigned int u32;
typedef unsigned short u16;
typedef float f32x2 __attribute__((ext_vector_type(2)));
typedef float f32x4 __attribute__((ext_vector_type(4)));
typedef short bf16x8 __attribute__((ext_vector_type(8)));

// stats slots (each slot = 2 floats: sum, sumsq)
#define ST_Y0 0
#define ST_W0 64
#define ST_Y1 72
#define ST_W1 136
#define ST_Y2 144
#define ST_W2 272
#define ST_LIN 288

static __device__ __forceinline__ float bf2f(u32 u){ return __uint_as_float(u<<16); }
static __device__ __forceinline__ u16 f2bf(float f){ u32 u=__float_as_uint(f); return (u16)((u + 0x7FFFu + ((u>>16)&1u))>>16); }

static __device__ __forceinline__ f32x2 pk_add(f32x2 a, f32x2 b){
  f32x2 d; asm("v_pk_add_f32 %0, %1, %2" : "=v"(d) : "v"(a), "v"(b)); return d;
}
static __device__ __forceinline__ f32x2 pk_mul(f32x2 a, f32x2 b){
  f32x2 d; asm("v_pk_mul_f32 %0, %1, %2" : "=v"(d) : "v"(a), "v"(b)); return d;
}

static __device__ __forceinline__ f32x4 mfma16(bf16x8 a, bf16x8 b, f32x4 c){
  return __builtin_amdgcn_mfma_f32_16x16x32_bf16(a,b,c,0,0,0);
}

static __device__ __forceinline__ uint4 pack8(const float* v){
  uint4 r;
  r.x=(u32)f2bf(v[0])|((u32)f2bf(v[1])<<16);
  r.y=(u32)f2bf(v[2])|((u32)f2bf(v[3])<<16);
  r.z=(u32)f2bf(v[4])|((u32)f2bf(v[5])<<16);
  r.w=(u32)f2bf(v[6])|((u32)f2bf(v[7])<<16);
  return r;
}

// unpack 8 bf16 + affine + relu
static __device__ __forceinline__ void unp8_aff(uint4 r, const float* A, const float* C, int cb, float* o){
  o[0]=fmaxf(fmaf(bf2f(r.x&0xffffu),A[cb+0],C[cb+0]),0.f);
  o[1]=fmaxf(fmaf(bf2f(r.x>>16)    ,A[cb+1],C[cb+1]),0.f);
  o[2]=fmaxf(fmaf(bf2f(r.y&0xffffu),A[cb+2],C[cb+2]),0.f);
  o[3]=fmaxf(fmaf(bf2f(r.y>>16)    ,A[cb+3],C[cb+3]),0.f);
  o[4]=fmaxf(fmaf(bf2f(r.z&0xffffu),A[cb+4],C[cb+4]),0.f);
  o[5]=fmaxf(fmaf(bf2f(r.z>>16)    ,A[cb+5],C[cb+5]),0.f);
  o[6]=fmaxf(fmaf(bf2f(r.w&0xffffu),A[cb+6],C[cb+6]),0.f);
  o[7]=fmaxf(fmaf(bf2f(r.w>>16)    ,A[cb+7],C[cb+7]),0.f);
}

// DPP helpers
template<int CTRL, int RMASK>
static __device__ __forceinline__ u32 dppmax(u32 m){
  u32 t=(u32)__builtin_amdgcn_update_dpp(0, (int)m, CTRL, RMASK, 0xf, false);
  return t>m ? t : m;
}
template<int CTRL, int RMASK>
static __device__ __forceinline__ float dppadd1(float v){
  float t=__uint_as_float((u32)__builtin_amdgcn_update_dpp(0,(int)__float_as_uint(v),CTRL,RMASK,0xf,false));
  return v+t;
}
static __device__ __forceinline__ float dppsum(float v){
  v=dppadd1<0x111,0xf>(v);
  v=dppadd1<0x112,0xf>(v);
  v=dppadd1<0x114,0xf>(v);
  v=dppadd1<0x118,0xf>(v);
  v=dppadd1<0x142,0xa>(v);
  v=dppadd1<0x143,0xc>(v);
  return v;
}
static __device__ __forceinline__ float rl63(float v){
  return __uint_as_float((u32)__builtin_amdgcn_readlane((int)__float_as_uint(v),63));
}

// ---------------- FPS: 256 threads, parallel (val,idx) local argmax (short post-reduce path) ----------------
__global__ __launch_bounds__(256) void k_fps(const float* __restrict__ xyz,
                                             float* __restrict__ fpsq, float* __restrict__ outx){
  __shared__ float X[NN], Y[NN], Z[NN];
  __shared__ float QX[SS], QY[SS], QZ[SS];
  __shared__ u64 red[2][4];
  int b=blockIdx.x, t=threadIdx.x;
  const float* xb=xyz+(size_t)b*3*NN;
  for (int i=t;i<NN;i+=256){ X[i]=xb[i]; Y[i]=xb[NN+i]; Z[i]=xb[2*NN+i]; }
  __syncthreads();
  f32x2 px[8],py[8],pz[8],dd[8];
  #pragma unroll
  for (int k=0;k<8;k++){
    int i=t*16+2*k;
    px[k].x=X[i]; px[k].y=X[i+1];
    py[k].x=Y[i]; py[k].y=Y[i+1];
    pz[k].x=Z[i]; pz[k].y=Z[i+1];
    dd[k].x=1e10f; dd[k].y=1e10f;
  }
  int wv=t>>6, ln=t&63;
  int far=0;
  for (int s=0;s<SS;s++){
    float fx=X[far], fy=Y[far], fz=Z[far];
    if (t==0){ QX[s]=fx; QY[s]=fy; QZ[s]=fz; }
    f32x2 nfx, nfy, nfz;
    nfx.x=-fx; nfx.y=-fx; nfy.x=-fy; nfy.y=-fy; nfz.x=-fz; nfz.y=-fz;
    #pragma unroll
    for (int k=0;k<8;k++){
      f32x2 dx=pk_add(px[k],nfx);      // == px - fx (IEEE: a-b = a+(-b))
      f32x2 xx=pk_mul(dx,dx);
      f32x2 dy=pk_add(py[k],nfy);
      f32x2 yy=pk_mul(dy,dy);
      f32x2 dz=pk_add(pz[k],nfz);
      f32x2 zz=pk_mul(dz,dz);
      f32x2 s1=pk_add(xx,yy);
      f32x2 d2=pk_add(s1,zz);          // ((dx^2+dy^2)+dz^2), ref order
      dd[k].x=fminf(dd[k].x,d2.x);
      dd[k].y=fminf(dd[k].y,d2.y);
    }
    // local (value,index) argmax tree; lower index wins ties (strict > to switch).
    // Computed in parallel with / independent of the cross-lane reduce.
    float bv[8]; int bi[8];
    #pragma unroll
    for (int k=0;k<8;k++){
      bool sw = dd[k].y > dd[k].x;
      bv[k] = sw ? dd[k].y : dd[k].x;
      bi[k] = t*16 + 2*k + (sw?1:0);
    }
    #pragma unroll
    for (int st=1; st<8; st<<=1){
      #pragma unroll
      for (int k=0;k<8;k+=st*2){
        bool sw = bv[k+st] > bv[k];
        bv[k] = sw ? bv[k+st] : bv[k];
        bi[k] = sw ? bi[k+st] : bi[k];
      }
    }
    float lmax=bv[0]; int lidx=bi[0];
    u32 m=__float_as_uint(lmax);
    // row-wise DPP reduce, then SALU combine of the 4 row maxima
    m=dppmax<0x111,0xf>(m);
    m=dppmax<0x112,0xf>(m);
    m=dppmax<0x114,0xf>(m);
    m=dppmax<0x118,0xf>(m);
    u32 r15=(u32)__builtin_amdgcn_readlane((int)m,15);
    u32 r31=(u32)__builtin_amdgcn_readlane((int)m,31);
    u32 r47=(u32)__builtin_amdgcn_readlane((int)m,47);
    u32 r63=(u32)__builtin_amdgcn_readlane((int)m,63);
    u32 ab = r15>r31 ? r15 : r31;
    u32 cd = r47>r63 ? r47 : r63;
    u32 wmax = ab>cd ? ab : cd;
    // short post-reduce path: lowest matching lane (lane order == index order)
    u64 ball=__ballot(__float_as_uint(lmax)==wmax);
    u32 wl=(u32)__builtin_ctzll(ball);
    u32 widx=(u32)__builtin_amdgcn_readlane(lidx,wl);
    int pb=s&1;
    if (ln==0) red[pb][wv]=((u64)wmax<<32)|(u32)(4095u-widx);
    __syncthreads();
    // keys are positive finite doubles -> f64 max == u64 max
    const double* rd=(const double*)&red[pb][0];
    double g=fmax(fmax(rd[0],rd[1]),fmax(rd[2],rd[3]));
    far=4095-(int)(__double_as_longlong(g)&0xFFFull);
  }
  __syncthreads();
  for (int i=t;i<SS;i+=256){
    float qx=QX[i], qy=QY[i], qz=QZ[i];
    float* q=&fpsq[((size_t)b*SS+i)*3]; q[0]=qx; q[1]=qy; q[2]=qz;
    outx[b*3*SS+i]=qx; outx[b*3*SS+SS+i]=qy; outx[b*3*SS+2*SS+i]=qz;
  }
}

// ---------------- KNN (blocks 0-1023) + featT/lwbf (1024-1279) + prep (1280) ----------------
#define KSTR 68
__global__ __launch_bounds__(512) void k_knnft(const float* __restrict__ xyz, const float* __restrict__ fpsq,
    int* __restrict__ kidx,
    const float* __restrict__ f, float* __restrict__ ft,
    const float* __restrict__ ww0,const float* __restrict__ ww1,const float* __restrict__ ww2,
    const float* __restrict__ lw, u16* __restrict__ lwbf,
    float* __restrict__ wt0,float* __restrict__ wt1,float* __restrict__ wt2,
    float* __restrict__ statsf){
  extern __shared__ char smem[];
  int blk=blockIdx.x; int t=threadIdx.x;
  if (blk>=1024){
    if (blk==1280){
      for (int i=t;i<1024;i+=512) statsf[i]=0.f;
      for (int i=t;i<8*3;i+=512){ int o=i/3,k=i%3; wt0[k*8+o]=ww0[i]; }
      for (int i=t;i<8*8;i+=512){ int o=i>>3,k=i&7; wt1[k*8+o]=ww1[i]; }
      for (int i=t;i<16*8;i+=512){ int o=i>>3,k=i&7; wt2[k*16+o]=ww2[i]; }
      return;
    }
    // lwbf chunk (1024 elems per block)
    {
      int base2=(blk-1024)*1024;
      for (int i=t;i<1024;i+=512) lwbf[base2+i]=f2bf(lw[base2+i]);
    }
    // feature transpose: 2 tiles per block
    float (*tile)[64][65]=(float(*)[64][65])smem;
    int sub=t>>8, tt=t&255;
    int tileIdx=(blk-1024)*2+sub;
    int b=tileIdx>>6; int n0=(tileIdx&63)*64;
    const float* fb=f+(size_t)b*64*NN;
    int c0=tt>>6, nn=tt&63;
    #pragma unroll
    for (int it=0;it<16;it++){ int c=c0+it*4; tile[sub][c][nn]=fb[(size_t)c*NN+n0+nn]; }
    __syncthreads();
    int cc=tt&63, n1=tt>>6;
    float* fo=ft+((size_t)b*NN+n0)*64;
    #pragma unroll
    for (int it=0;it<16;it++){ int n=n1+it*4; fo[(size_t)n*64+cc]=tile[sub][cc][n]; }
    return;
  }
  float* xs=(float*)smem;
  float* ys=xs+64*KSTR;
  float* zs=ys+64*KSTR;
  float* pn=zs+64*KSTR;
  int b=blk>>7; int s0=(blk&127)*8;
  const float* xb=xyz+(size_t)b*3*NN;
  for (int i=t;i<NN;i+=512){
    float x=xb[i],y=xb[NN+i],z=xb[2*NN+i];
    int slot=(i>>6)*KSTR+(i&63);
    xs[slot]=x; ys[slot]=y; zs[slot]=z;
    pn[slot]=__fadd_rn(__fadd_rn(__fmul_rn(x,x),__fmul_rn(y,y)),__fmul_rn(z,z));
  }
  __syncthreads();
  int wv=t>>6, ln=t&63;
  int s=s0+wv;
  const float* q=&fpsq[((size_t)b*SS+s)*3];
  float qx=q[0],qy=q[1],qz=q[2];
  float qn=__fadd_rn(__fadd_rn(__fmul_rn(qx,qx),__fmul_rn(qy,qy)),__fmul_rn(qz,qz));
  f32x2 qxx,qyy,qzz,qnn,mtwo;
  qxx.x=qx;qxx.y=qx; qyy.x=qy;qyy.y=qy; qzz.x=qz;qzz.y=qz; qnn.x=qn;qnn.y=qn;
  mtwo.x=-2.f; mtwo.y=-2.f;
  const float4* Xp=(const float4*)(xs+ln*KSTR);
  const float4* Yp=(const float4*)(ys+ln*KSTR);
  const float4* Zp=(const float4*)(zs+ln*KSTR);
  const float4* Pp=(const float4*)(pn+ln*KSTR);
  int base=ln*64;
  u64 v[64];
  #pragma unroll
  for (int g=0;g<16;g++){
    float4 x4=Xp[g], y4=Yp[g], z4=Zp[g], p4=Pp[g];
    #pragma unroll
    for (int h=0;h<2;h++){
      f32x2 px2,py2,pz2,pn2;
      if (h==0){ px2.x=x4.x;px2.y=x4.y; py2.x=y4.x;py2.y=y4.y; pz2.x=z4.x;pz2.y=z4.y; pn2.x=p4.x;pn2.y=p4.y; }
      else     { px2.x=x4.z;px2.y=x4.w; py2.x=y4.z;py2.y=y4.w; pz2.x=z4.z;pz2.y=z4.w; pn2.x=p4.z;pn2.y=p4.w; }
      f32x2 m1=pk_mul(qxx,px2);
      f32x2 mm=pk_mul(qyy,py2);
      f32x2 a1=pk_add(m1,mm);
      f32x2 m3=pk_mul(qzz,pz2);
      f32x2 dt=pk_add(a1,m3);
      f32x2 qp=pk_add(qnn,pn2);
      f32x2 nd=pk_mul(dt,mtwo);
      f32x2 d2=pk_add(qp,nd);
      #pragma unroll
      for (int e=0;e<2;e++){
        u32 bu=__float_as_uint(e?d2.y:d2.x);
        bu = ((int)bu<0)? ~bu : (bu|0x80000000u);
        v[g*4+h*2+e]=((u64)bu<<32)|(u32)(base+g*4+h*2+e);
      }
    }
  }
  u64 cand[8];
  #pragma unroll
  for (int gg=0;gg<8;gg++){
    u64 c=v[gg*8];
    #pragma unroll
    for (int j=1;j<8;j++){ u64 x=v[gg*8+j]; c = x<c?x:c; }
    cand[gg]=c;
  }
  u64 best=cand[0];
  #pragma unroll
  for (int gg=1;gg<8;gg++){ u64 x=cand[gg]; best = x<best?x:best; }
  int my=0;
  #pragma unroll 1
  for (int r=0;r<KK;r++){
    u64 w=best;
    #pragma unroll
    for (int m=1;m<64;m<<=1){ u64 o=__shfl_xor(w,m,64); w = o<w?o:w; }
    if (ln==r) my=(int)(w&0xFFFull);
    if (best==w){
      #pragma unroll
      for (int gg=0;gg<8;gg++){
        if (cand[gg]==w){
          u64 c=~0ull;
          #pragma unroll
          for (int j=0;j<8;j++){ u64 x=v[gg*8+j]; x = x>w ? x : ~0ull; c = x<c?x:c; }
          cand[gg]=c;
        }
      }
      u64 nb=cand[0];
      #pragma unroll
      for (int gg=1;gg<8;gg++){ u64 x=cand[gg]; nb = x<nb?x:nb; }
      best=nb;
    }
  }
  if (ln<KK) kidx[(((size_t)b*SS+s)<<5)+ln]=my;
}

// ---------------- layer 0 (MFMA): gather + 67->64 via C-operand + wnet 3->8 (+stats) ----------------
__global__ __launch_bounds__(256) void k_l0(const float* __restrict__ xyz, const float* __restrict__ ft,
    const float* __restrict__ fpsq, const int* __restrict__ kidx,
    const float* __restrict__ w0, const float* __restrict__ wt0,
    u16* __restrict__ y0, float* __restrict__ wl0, float* __restrict__ statsf){
  __shared__ u16 Bw[64*72];
  __shared__ float gt[256][4];
  __shared__ int jt[256];
  __shared__ float pS[4][64], pQ[4][64];
  __shared__ float pWS[4][8], pWQ[4][8];
  int t=threadIdx.x; int wv=t>>6, ln=t&63;
  int p=blockIdx.x*256+t;
  int b=p>>15;
  int site=p>>5;
  int j=kidx[p];
  const float* xb=xyz+(size_t)b*3*NN;
  const float* q=fpsq+(size_t)site*3;
  float gx=xb[j]-q[0], gy=xb[NN+j]-q[1], gz=xb[2*NN+j]-q[2];
  gt[t][0]=gx; gt[t][1]=gy; gt[t][2]=gz; gt[t][3]=0.f; jt[t]=j;
  for (int i=t;i<4096;i+=256){ int col=i>>6,k=i&63; Bw[col*72+k]=f2bf(w0[col*67+3+k]); }
  __syncthreads();
  float wxc[4],wyc[4],wzc[4];
  #pragma unroll
  for (int n=0;n<4;n++){
    int c=n*16+(ln&15);
    wxc[n]=w0[c*67+0]; wyc[n]=w0[c*67+1]; wzc[n]=w0[c*67+2];
  }
  float sS[4]={0,0,0,0}, sQ[4]={0,0,0,0};
  int base=wv*64;
  #pragma unroll 1
  for (int rs=0;rs<4;rs++){
    int lrow=base+rs*16+(ln&15);
    int jr=jt[lrow];
    const float* fp=ft+((size_t)b*NN+jr)*64 + (ln>>4)*8;
    float4 fa=*(const float4*)fp, fb4=*(const float4*)(fp+4);
    float4 fc=*(const float4*)(fp+32), fd=*(const float4*)(fp+36);
    float va[8]={fa.x,fa.y,fa.z,fa.w,fb4.x,fb4.y,fb4.z,fb4.w};
    float vb[8]={fc.x,fc.y,fc.z,fc.w,fd.x,fd.y,fd.z,fd.w};
    bf16x8 a0,a1;
    #pragma unroll
    for (int e=0;e<8;e++){ ((u16*)&a0)[e]=(short)f2bf(va[e]); ((u16*)&a1)[e]=(short)f2bf(vb[e]); }
    int r0=base+rs*16+(ln>>4)*4;
    float4 g0v4=*(const float4*)&gt[r0+0][0];
    float4 g1v4=*(const float4*)&gt[r0+1][0];
    float4 g2v4=*(const float4*)&gt[r0+2][0];
    float4 g3v4=*(const float4*)&gt[r0+3][0];
    float gxr[4]={g0v4.x,g1v4.x,g2v4.x,g3v4.x};
    float gyr[4]={g0v4.y,g1v4.y,g2v4.y,g3v4.y};
    float gzr[4]={g0v4.z,g1v4.z,g2v4.z,g3v4.z};
    int pr=blockIdx.x*256+base+rs*16;
    #pragma unroll
    for (int n=0;n<4;n++){
      const u16* bp=&Bw[(size_t)(n*16+(ln&15))*72 + (ln>>4)*8];
      bf16x8 b0=*(const bf16x8*)bp;
      bf16x8 b1=*(const bf16x8*)(bp+32);
      f32x4 acc;
      #pragma unroll
      for (int i=0;i<4;i++) acc[i]=fmaf(gxr[i],wxc[n],fmaf(gyr[i],wyc[n],gzr[i]*wzc[n]));
      acc=mfma16(a0,b0,acc);
      acc=mfma16(a1,b1,acc);
      #pragma unroll
      for (int i=0;i<4;i++){
        int row=(ln>>4)*4+i;
        y0[(size_t)(pr+row)*64 + n*16 + (ln&15)]=f2bf(acc[i]);
        sS[n]+=acc[i]; sQ[n]=fmaf(acc[i],acc[i],sQ[n]);
      }
    }
  }
  #pragma unroll
  for (int n=0;n<4;n++){
    sS[n]+=__shfl_xor(sS[n],16,64); sS[n]+=__shfl_xor(sS[n],32,64);
    sQ[n]+=__shfl_xor(sQ[n],16,64); sQ[n]+=__shfl_xor(sQ[n],32,64);
  }
  if (ln<16){
    #pragma unroll
    for (int n=0;n<4;n++){ pS[wv][n*16+ln]=sS[n]; pQ[wv][n*16+ln]=sQ[n]; }
  }
  float wa[8];
  #pragma unroll
  for (int o=0;o<8;o++) wa[o]=fmaf(gx,wt0[o],fmaf(gy,wt0[8+o],gz*wt0[16+o]));
  float4* wr=(float4*)(wl0+(size_t)p*8);
  wr[0]=make_float4(wa[0],wa[1],wa[2],wa[3]);
  wr[1]=make_float4(wa[4],wa[5],wa[6],wa[7]);
  float wS[8],wQ[8];
  #pragma unroll
  for (int o=0;o<8;o++){
    wS[o]=rl63(dppsum(wa[o]));
    wQ[o]=rl63(dppsum(wa[o]*wa[o]));
  }
  if (ln==0){
    #pragma unroll
    for (int o=0;o<8;o++){ pWS[wv][o]=wS[o]; pWQ[wv][o]=wQ[o]; }
  }
  __syncthreads();
  if (t<64){
    float S=pS[0][t]+pS[1][t]+pS[2][t]+pS[3][t];
    float Q=pQ[0][t]+pQ[1][t]+pQ[2][t]+pQ[3][t];
    atomicAdd(&statsf[2*(ST_Y0+t)],S); atomicAdd(&statsf[2*(ST_Y0+t)+1],Q);
  } else if (t<72){
    int c=t-64;
    float S=pWS[0][c]+pWS[1][c]+pWS[2][c]+pWS[3][c];
    float Q=pWQ[0][c]+pWQ[1][c]+pWQ[2][c]+pWQ[3][c];
    atomicAdd(&statsf[2*(ST_W0+c)],S); atomicAdd(&statsf[2*(ST_W0+c)+1],Q);
  }
}

// ---------------- layer 1 (MFMA): BN0+relu -> 64->64 ; wnet 8->8 (+stats from acc) ----------------
__global__ __launch_bounds__(256) void k_l1(const u16* __restrict__ y0, const float* __restrict__ wl0,
    const float* __restrict__ w1, const float* __restrict__ wt1,
    const float* __restrict__ statsf,
    const float* __restrict__ g0v, const float* __restrict__ be0v,
    const float* __restrict__ wg0v, const float* __restrict__ wbe0v,
    u16* __restrict__ y1, float* __restrict__ wl1, float* __restrict__ statso){
  __shared__ float A0[64],C0[64],AW[8],CW[8];
  __shared__ u16 Bw[64*72];
  __shared__ u16 Atile[4][16*72];
  __shared__ float pS[4][64], pQ[4][64];
  __shared__ float pWS[4][8], pWQ[4][8];
  int t=threadIdx.x; int wv=t>>6, ln=t&63;
  if (t<64){
    float sm=statsf[(ST_Y0+t)*2], sq=statsf[(ST_Y0+t)*2+1];
    float mean=sm*(1.f/PP), var=fmaxf(sq*(1.f/PP)-mean*mean,0.f);
    float a=g0v[t]*rsqrtf(var+1e-5f); A0[t]=a; C0[t]=be0v[t]-mean*a;
  } else if (t<72){
    int c=t-64;
    float sm=statsf[(ST_W0+c)*2], sq=statsf[(ST_W0+c)*2+1];
    float mean=sm*(1.f/PP), var=fmaxf(sq*(1.f/PP)-mean*mean,0.f);
    float a=wg0v[c]*rsqrtf(var+1e-5f); AW[c]=a; CW[c]=wbe0v[c]-mean*a;
  }
  for (int i=t;i<4096;i+=256){ Bw[(i>>6)*72+(i&63)]=f2bf(w1[i]); }
  __syncthreads();
  bf16x8 bfr[4][2];
  #pragma unroll
  for (int n=0;n<4;n++){
    const u16* bp=&Bw[(size_t)(n*16+(ln&15))*72 + (ln>>4)*8];
    bfr[n][0]=*(const bf16x8*)bp;
    bfr[n][1]=*(const bf16x8*)(bp+32);
  }
  float sS[4]={0,0,0,0}, sQ[4]={0,0,0,0};
  int p0=blockIdx.x*256 + wv*64;
  u16* At=Atile[wv];
  #pragma unroll 1
  for (int rs=0;rs<4;rs++){
    int pr=p0+rs*16;
    {
      const u16* ysrc=y0+(size_t)pr*64 + ln*16;
      uint4 raw0=*(const uint4*)ysrc;
      uint4 raw1=*(const uint4*)(ysrc+8);
      int row=ln>>2, cb=(ln&3)*16;
      float tmp[8];
      unp8_aff(raw0,A0,C0,cb,tmp);
      *(uint4*)&At[row*72+cb]=pack8(tmp);
      unp8_aff(raw1,A0,C0,cb+8,tmp);
      *(uint4*)&At[row*72+cb+8]=pack8(tmp);
    }
    const u16* ap=&At[(ln&15)*72 + (ln>>4)*8];
    bf16x8 a0=*(const bf16x8*)ap;
    bf16x8 a1=*(const bf16x8*)(ap+32);
    #pragma unroll
    for (int n=0;n<4;n++){
      f32x4 acc={0.f,0.f,0.f,0.f};
      acc=mfma16(a0,bfr[n][0],acc);
      acc=mfma16(a1,bfr[n][1],acc);
      #pragma unroll
      for (int i=0;i<4;i++){
        int row=(ln>>4)*4+i;
        y1[(size_t)(pr+row)*64 + n*16 + (ln&15)]=f2bf(acc[i]);
        sS[n]+=acc[i]; sQ[n]=fmaf(acc[i],acc[i],sQ[n]);
      }
    }
  }
  #pragma unroll
  for (int n=0;n<4;n++){
    sS[n]+=__shfl_xor(sS[n],16,64); sS[n]+=__shfl_xor(sS[n],32,64);
    sQ[n]+=__shfl_xor(sQ[n],16,64); sQ[n]+=__shfl_xor(sQ[n],32,64);
  }
  if (ln<16){
    #pragma unroll
    for (int n=0;n<4;n++){ pS[wv][n*16+ln]=sS[n]; pQ[wv][n*16+ln]=sQ[n]; }
  }
  int p=blockIdx.x*256+t;
  const float4* wvp=(const float4*)(wl0+(size_t)p*8);
  float4 v0=wvp[0], v1=wvp[1];
  float wi[8]={v0.x,v0.y,v0.z,v0.w,v1.x,v1.y,v1.z,v1.w};
  float wo[8];
  #pragma unroll
  for (int o=0;o<8;o++) wo[o]=0.f;
  #pragma unroll
  for (int k=0;k<8;k++){
    float xr=fmaxf(fmaf(wi[k],AW[k],CW[k]),0.f);
    #pragma unroll
    for (int o=0;o<8;o++) wo[o]=fmaf(xr,wt1[k*8+o],wo[o]);
  }
  float4* wr=(float4*)(wl1+(size_t)p*8);
  wr[0]=make_float4(wo[0],wo[1],wo[2],wo[3]);
  wr[1]=make_float4(wo[4],wo[5],wo[6],wo[7]);
  float wS[8],wQ[8];
  #pragma unroll
  for (int o=0;o<8;o++){
    wS[o]=rl63(dppsum(wo[o]));
    wQ[o]=rl63(dppsum(wo[o]*wo[o]));
  }
  if (ln==0){
    #pragma unroll
    for (int o=0;o<8;o++){ pWS[wv][o]=wS[o]; pWQ[wv][o]=wQ[o]; }
  }
  __syncthreads();
  if (t<64){
    float S=pS[0][t]+pS[1][t]+pS[2][t]+pS[3][t];
    float Q=pQ[0][t]+pQ[1][t]+pQ[2][t]+pQ[3][t];
    atomicAdd(&statso[2*(ST_Y1+t)],S); atomicAdd(&statso[2*(ST_Y1+t)+1],Q);
  } else if (t<72){
    int c=t-64;
    float S=pWS[0][c]+pWS[1][c]+pWS[2][c]+pWS[3][c];
    float Q=pWQ[0][c]+pWQ[1][c]+pWQ[2][c]+pWQ[3][c];
    atomicAdd(&statso[2*(ST_W1+c)],S); atomicAdd(&statso[2*(ST_W1+c)+1],Q);
  }
}

// ---------------- layer 2 (MFMA): BN1+relu -> 64->128 ; wnet 8->16 (+stats from acc) ----------------
__global__ __launch_bounds__(256) void k_l2(const u16* __restrict__ y1, const float* __restrict__ wl1,
    const float* __restrict__ w2, const float* __restrict__ wt2,
    const float* __restrict__ statsf,
    const float* __restrict__ g1v, const float* __restrict__ be1v,
    const float* __restrict__ wg1v, const float* __restrict__ wbe1v,
    u16* __restrict__ y2, float* __restrict__ wl2, float* __restrict__ statso){
  __shared__ float A1[64],C1[64],AW[8],CW[8];
  __shared__ u16 Bw[128*72];
  __shared__ u16 Atile[4][16*72];
  __shared__ float pS[4][128], pQ[4][128];
  __shared__ float pWS[4][16], pWQ[4][16];
  int t=threadIdx.x; int wv=t>>6, ln=t&63;
  if (t<64){
    float sm=statsf[(ST_Y1+t)*2], sq=statsf[(ST_Y1+t)*2+1];
    float mean=sm*(1.f/PP), var=fmaxf(sq*(1.f/PP)-mean*mean,0.f);
    float a=g1v[t]*rsqrtf(var+1e-5f); A1[t]=a; C1[t]=be1v[t]-mean*a;
  } else if (t<72){
    int c=t-64;
    float sm=statsf[(ST_W1+c)*2], sq=statsf[(ST_W1+c)*2+1];
    float mean=sm*(1.f/PP), var=fmaxf(sq*(1.f/PP)-mean*mean,0.f);
    float a=wg1v[c]*rsqrtf(var+1e-5f); AW[c]=a; CW[c]=wbe1v[c]-mean*a;
  }
  for (int i=t;i<8192;i+=256){ Bw[(i>>6)*72+(i&63)]=f2bf(w2[i]); }
  __syncthreads();
  float sS[8]={0,0,0,0,0,0,0,0}, sQ[8]={0,0,0,0,0,0,0,0};
  int p0=blockIdx.x*256 + wv*64;
  u16* At=Atile[wv];
  #pragma unroll 1
  for (int rs=0;rs<4;rs++){
    int pr=p0+rs*16;
    {
      const u16* ysrc=y1+(size_t)pr*64 + ln*16;
      uint4 raw0=*(const uint4*)ysrc;
      uint4 raw1=*(const uint4*)(ysrc+8);
      int row=ln>>2, cb=(ln&3)*16;
      float tmp[8];
      unp8_aff(raw0,A1,C1,cb,tmp);
      *(uint4*)&At[row*72+cb]=pack8(tmp);
      unp8_aff(raw1,A1,C1,cb+8,tmp);
      *(uint4*)&At[row*72+cb+8]=pack8(tmp);
    }
    const u16* ap=&At[(ln&15)*72 + (ln>>4)*8];
    bf16x8 a0=*(const bf16x8*)ap;
    bf16x8 a1=*(const bf16x8*)(ap+32);
    #pragma unroll
    for (int n=0;n<8;n++){
      const u16* bp=&Bw[(size_t)(n*16+(ln&15))*72 + (ln>>4)*8];
      bf16x8 b0=*(const bf16x8*)bp;
      bf16x8 b1=*(const bf16x8*)(bp+32);
      f32x4 acc={0.f,0.f,0.f,0.f};
      acc=mfma16(a0,b0,acc);
      acc=mfma16(a1,b1,acc);
      #pragma unroll
      for (int i=0;i<4;i++){
        int row=(ln>>4)*4+i;
        y2[(size_t)(pr+row)*128 + n*16 + (ln&15)]=f2bf(acc[i]);
        sS[n]+=acc[i]; sQ[n]=fmaf(acc[i],acc[i],sQ[n]);
      }
    }
  }
  #pragma unroll
  for (int n=0;n<8;n++){
    sS[n]+=__shfl_xor(sS[n],16,64); sS[n]+=__shfl_xor(sS[n],32,64);
    sQ[n]+=__shfl_xor(sQ[n],16,64); sQ[n]+=__shfl_xor(sQ[n],32,64);
  }
  if (ln<16){
    #pragma unroll
    for (int n=0;n<8;n++){ pS[wv][n*16+ln]=sS[n]; pQ[wv][n*16+ln]=sQ[n]; }
  }
  int p=blockIdx.x*256+t;
  const float4* wvp=(const float4*)(wl1+(size_t)p*8);
  float4 v0=wvp[0], v1=wvp[1];
  float wi[8]={v0.x,v0.y,v0.z,v0.w,v1.x,v1.y,v1.z,v1.w};
  float wo[16];
  #pragma unroll
  for (int o=0;o<16;o++) wo[o]=0.f;
  #pragma unroll
  for (int k=0;k<8;k++){
    float xr=fmaxf(fmaf(wi[k],AW[k],CW[k]),0.f);
    #pragma unroll
    for (int o=0;o<16;o++) wo[o]=fmaf(xr,wt2[k*16+o],wo[o]);
  }
  float4* wr=(float4*)(wl2+(size_t)p*16);
  wr[0]=make_float4(wo[0],wo[1],wo[2],wo[3]);
  wr[1]=make_float4(wo[4],wo[5],wo[6],wo[7]);
  wr[2]=make_float4(wo[8],wo[9],wo[10],wo[11]);
  wr[3]=make_float4(wo[12],wo[13],wo[14],wo[15]);
  float wS[16],wQ[16];
  #pragma unroll
  for (int o=0;o<16;o++){
    wS[o]=rl63(dppsum(wo[o]));
    wQ[o]=rl63(dppsum(wo[o]*wo[o]));
  }
  if (ln==0){
    #pragma unroll
    for (int o=0;o<16;o++){ pWS[wv][o]=wS[o]; pWQ[wv][o]=wQ[o]; }
  }
  __syncthreads();
  if (t<128){
    float S=pS[0][t]+pS[1][t]+pS[2][t]+pS[3][t];
    float Q=pQ[0][t]+pQ[1][t]+pQ[2][t]+pQ[3][t];
    atomicAdd(&statso[2*(ST_Y2+t)],S); atomicAdd(&statso[2*(ST_Y2+t)+1],Q);
  } else if (t<144){
    int c=t-128;
    float S=pWS[0][c]+pWS[1][c]+pWS[2][c]+pWS[3][c];
    float Q=pWQ[0][c]+pWQ[1][c]+pWQ[2][c]+pWQ[3][c];
    atomicAdd(&statso[2*(ST_W2+c)],S); atomicAdd(&statso[2*(ST_W2+c)+1],Q);
  }
}

// ---------------- fused agg+lin: pool 16 sites to LDS, then MFMA vs lwbf (+lin stats) ----------------
__global__ __launch_bounds__(256) void k_agglin(const u16* __restrict__ y2, const float* __restrict__ wl2,
    const float* __restrict__ statsf,
    const float* __restrict__ g2v, const float* __restrict__ be2v,
    const float* __restrict__ wg2v, const float* __restrict__ wbe2v,
    const u16* __restrict__ lwbf, float* __restrict__ lin, float* __restrict__ outst){
  __shared__ float A2[128],C2[128],AW[16],CW[16];
  __shared__ float wt[32*16];
  __shared__ u16 aggt[16][2056];
  __shared__ float pS[4][32], pQ[4][32];
  int t=threadIdx.x; int wv=t>>6, ln=t&63;
  int s0=blockIdx.x*16;
  if (t<128){
    float sm=statsf[(ST_Y2+t)*2], sq=statsf[(ST_Y2+t)*2+1];
    float mean=sm*(1.f/PP), var=fmaxf(sq*(1.f/PP)-mean*mean,0.f);
    float a=g2v[t]*rsqrtf(var+1e-5f); A2[t]=a; C2[t]=be2v[t]-mean*a;
  } else if (t<144){
    int c=t-128;
    float sm=statsf[(ST_W2+c)*2], sq=statsf[(ST_W2+c)*2+1];
    float mean=sm*(1.f/PP), var=fmaxf(sq*(1.f/PP)-mean*mean,0.f);
    float a=wg2v[c]*rsqrtf(var+1e-5f); AW[c]=a; CW[c]=wbe2v[c]-mean*a;
  }
  __syncthreads();
  int d=t>>1, cb=(t&1)*8;
  float a2d=A2[d], c2d=C2[d];
  #pragma unroll 1
  for (int si=0; si<16; si++){
    int site=s0+si;
    #pragma unroll
    for (int it=0; it<2; it++){
      int i=t+it*256;
      float x=wl2[(size_t)site*512+i]; int c=i&15;
      wt[i]=fmaxf(fmaf(x,AW[c],CW[c]),0.f);
    }
    __syncthreads();
    float acc[8];
    #pragma unroll
    for (int e=0;e<8;e++) acc[e]=0.f;
    const u16* ys=y2+(size_t)site*4096;
    #pragma unroll 4
    for (int kq=0;kq<32;kq++){
      float nv=fmaxf(fmaf(bf2f((u32)ys[kq*128+d]),a2d,c2d),0.f);
      #pragma unroll
      for (int e=0;e<8;e++) acc[e]=fmaf(nv,wt[kq*16+cb+e],acc[e]);
    }
    *(uint4*)&aggt[si][d*16+cb]=pack8(acc);
    __syncthreads();
  }
  // phase B: lin MFMA from LDS aggt
  const u16* arow=&aggt[ln&15][(ln>>4)*8];
  const u16* b0p=lwbf+(size_t)(wv*32+(ln&15))*2048 + (ln>>4)*8;
  const u16* b1p=b0p + (size_t)16*2048;
  f32x4 acc0={0.f,0.f,0.f,0.f}, acc1={0.f,0.f,0.f,0.f};
  #pragma unroll 4
  for (int kb=0;kb<2048;kb+=32){
    bf16x8 a=*(const bf16x8*)(arow+kb);
    bf16x8 b0=*(const bf16x8*)(b0p+kb);
    bf16x8 b1=*(const bf16x8*)(b1p+kb);
    acc0=mfma16(a,b0,acc0);
    acc1=mfma16(a,b1,acc1);
  }
  float sS0=0.f,sQ0=0.f,sS1=0.f,sQ1=0.f;
  #pragma unroll
  for (int i=0;i<4;i++){
    int row=(ln>>4)*4+i;
    lin[(size_t)(s0+row)*128 + wv*32 + (ln&15)]=acc0[i];
    lin[(size_t)(s0+row)*128 + wv*32 + 16 + (ln&15)]=acc1[i];
    sS0+=acc0[i]; sQ0=fmaf(acc0[i],acc0[i],sQ0);
    sS1+=acc1[i]; sQ1=fmaf(acc1[i],acc1[i],sQ1);
  }
  sS0+=__shfl_xor(sS0,16,64); sS0+=__shfl_xor(sS0,32,64);
  sQ0+=__shfl_xor(sQ0,16,64); sQ0+=__shfl_xor(sQ0,32,64);
  sS1+=__shfl_xor(sS1,16,64); sS1+=__shfl_xor(sS1,32,64);
  sQ1+=__shfl_xor(sQ1,16,64); sQ1+=__shfl_xor(sQ1,32,64);
  if (ln<16){ pS[wv][ln]=sS0; pS[wv][16+ln]=sS1; pQ[wv][ln]=sQ0; pQ[wv][16+ln]=sQ1; }
  __syncthreads();
  if (t<128){
    float S=pS[t>>5][t&31], Q=pQ[t>>5][t&31];
    atomicAdd(&outst[2*t],S); atomicAdd(&outst[2*t+1],Q);
  }
}

// ---------------- final BN + relu + transpose -> out [B,128,S] ----------------
__global__ __launch_bounds__(256) void k_out(const float* __restrict__ lin, const float* __restrict__ statsf,
    const float* __restrict__ lg, const float* __restrict__ lbe, float* __restrict__ outf){
  int t=blockIdx.x*256+threadIdx.x;
  int s4=(t&255)*4; int o=(t>>8)&127; int b=t>>15;
  float sm=statsf[(ST_LIN+o)*2], sq=statsf[(ST_LIN+o)*2+1];
  float mean=sm*(1.f/8192.f), var=fmaxf(sq*(1.f/8192.f)-mean*mean,0.f);
  float a=lg[o]*rsqrtf(var+1e-5f), cc=lbe[o]-mean*a;
  float v0=lin[((size_t)b*SS+s4+0)*128+o];
  float v1=lin[((size_t)b*SS+s4+1)*128+o];
  float v2=lin[((size_t)b*SS+s4+2)*128+o];
  float v3=lin[((size_t)b*SS+s4+3)*128+o];
  float4 r=make_float4(fmaxf(fmaf(v0,a,cc),0.f),fmaxf(fmaf(v1,a,cc),0.f),
                       fmaxf(fmaf(v2,a,cc),0.f),fmaxf(fmaf(v3,a,cc),0.f));
  *(float4*)(outf+((size_t)b*128+o)*SS+s4)=r;
}

extern "C" void kernel_launch(void* const* d_in, const int* in_sizes, int n_in,
                              void* d_out, int out_size, void* d_ws, size_t ws_size,
                              hipStream_t stream){
  (void)in_sizes;(void)n_in;(void)out_size;(void)ws_size;
  const float* xyz =(const float*)d_in[0];
  const float* feat=(const float*)d_in[1];
  const float* w0=(const float*)d_in[2];  const float* g0=(const float*)d_in[4];  const float* be0=(const float*)d_in[5];
  const float* w1=(const float*)d_in[6];  const float* g1=(const float*)d_in[8];  const float* be1=(const float*)d_in[9];
  const float* w2=(const float*)d_in[10]; const float* g2=(const float*)d_in[12]; const float* be2=(const float*)d_in[13];
  const float* ww0=(const float*)d_in[14]; const float* wg0=(const float*)d_in[16]; const float* wbe0=(const float*)d_in[17];
  const float* ww1=(const float*)d_in[18]; const float* wg1=(const float*)d_in[20]; const float* wbe1=(const float*)d_in[21];
  const float* ww2=(const float*)d_in[22]; const float* wg2=(const float*)d_in[24]; const float* wbe2=(const float*)d_in[25];
  const float* lw=(const float*)d_in[26]; const float* lg=(const float*)d_in[28]; const float* lbe=(const float*)d_in[29];
  float* out=(float*)d_out;
  char* ws=(char*)d_ws;

  size_t cur=0;
  auto alloc=[&](size_t bytes)->size_t{ cur=(cur+255)&~(size_t)255; size_t o=cur; cur+=bytes; return o; };
  size_t o_stats=alloc(4096);
  size_t o_wt0 =alloc(3*8*4);
  size_t o_wt1 =alloc(8*8*4);
  size_t o_wt2 =alloc(8*16*4);
  size_t o_lwbf=alloc((size_t)128*2048*2);
  size_t o_fpsq=alloc((size_t)BB*SS*3*4);
  size_t o_kidx=alloc((size_t)PP*4);
  size_t o_ft  =alloc((size_t)BB*NN*64*4);
  size_t o_y0  =alloc((size_t)PP*64*2);
  size_t o_y1  =alloc((size_t)PP*64*2);
  size_t o_y2  =alloc((size_t)PP*128*2);
  size_t o_wl0 =alloc((size_t)PP*8*4);
  size_t o_wl1 =alloc((size_t)PP*8*4);
  size_t o_wl2 =alloc((size_t)PP*16*4);
  size_t o_lin =alloc((size_t)8192*128*4);

  float* statsf=(float*)(ws+o_stats);
  float* wt0=(float*)(ws+o_wt0); float* wt1=(float*)(ws+o_wt1); float* wt2=(float*)(ws+o_wt2);
  u16* lwbf=(u16*)(ws+o_lwbf);
  float* fpsq=(float*)(ws+o_fpsq); int* kidx=(int*)(ws+o_kidx);
  float* ft=(float*)(ws+o_ft);
  u16* y0=(u16*)(ws+o_y0); u16* y1=(u16*)(ws+o_y1); u16* y2=(u16*)(ws+o_y2);
  float* wl0=(float*)(ws+o_wl0); float* wl1=(float*)(ws+o_wl1); float* wl2=(float*)(ws+o_wl2);
  float* lin=(float*)(ws+o_lin);

  size_t knn_smem = (size_t)4*64*KSTR*4;             // 69632 B (covers featT tiles too)

  hipLaunchKernelGGL(k_fps,dim3(BB),dim3(256),0,stream,xyz,fpsq,out);
  hipLaunchKernelGGL(k_knnft,dim3(1281),dim3(512),knn_smem,stream,xyz,fpsq,kidx,
                     feat,ft,ww0,ww1,ww2,lw,lwbf,wt0,wt1,wt2,statsf);
  hipLaunchKernelGGL(k_l0,dim3(PP/256),dim3(256),0,stream,xyz,ft,fpsq,kidx,w0,wt0,y0,wl0,statsf);
  hipLaunchKernelGGL(k_l1,dim3(PP/256),dim3(256),0,stream,y0,wl0,w1,wt1,statsf,g0,be0,wg0,wbe0,y1,wl1,statsf);
  hipLaunchKernelGGL(k_l2,dim3(PP/256),dim3(256),0,stream,y1,wl1,w2,wt2,statsf,g1,be1,wg1,wbe1,y2,wl2,statsf);
  hipLaunchKernelGGL(k_agglin,dim3(512),dim3(256),0,stream,y2,wl2,statsf,g2,be2,wg2,wbe2,lwbf,lin,statsf+2*ST_LIN);
  hipLaunchKernelGGL(k_out,dim3(1024),dim3(256),0,stream,lin,statsf,lg,lbe,out+BB*3*SS);
}

// Round 17
// 1074.024 us; speedup vs baseline: 1.2063x; 1.2063x over previous
//
#include <hip/hip_runtime.h>
#include <hip/hip_bf16.h>

// PointConv SetAbstraction for MI355X. B=8,N=4096,S=1024,K=32,D=64.
#define BB 8
#define NN 4096
#define SS 1024
#define KK 32
#define PP (BB*SS*KK)   // 262144

typedef unsigned long long u64;
typedef unsigned int u32;
typedef unsigned short u16;
typedef float f32x2 __attribute__((ext_vector_type(2)));
typedef float f32x4 __attribute__((ext_vector_type(4)));
typedef short bf16x8 __attribute__((ext_vector_type(8)));

// stats slots (each slot = 2 floats: sum, sumsq)
#define ST_Y0 0
#define ST_W0 64
#define ST_Y1 72
#define ST_W1 136
#define ST_Y2 144
#define ST_W2 272
#define ST_LIN 288

static __device__ __forceinline__ float bf2f(u32 u){ return __uint_as_float(u<<16); }
static __device__ __forceinline__ u16 f2bf(float f){ u32 u=__float_as_uint(f); return (u16)((u + 0x7FFFu + ((u>>16)&1u))>>16); }

static __device__ __forceinline__ f32x2 pk_add(f32x2 a, f32x2 b){
  f32x2 d; asm("v_pk_add_f32 %0, %1, %2" : "=v"(d) : "v"(a), "v"(b)); return d;
}
static __device__ __forceinline__ f32x2 pk_mul(f32x2 a, f32x2 b){
  f32x2 d; asm("v_pk_mul_f32 %0, %1, %2" : "=v"(d) : "v"(a), "v"(b)); return d;
}

static __device__ __forceinline__ f32x4 mfma16(bf16x8 a, bf16x8 b, f32x4 c){
  return __builtin_amdgcn_mfma_f32_16x16x32_bf16(a,b,c,0,0,0);
}

static __device__ __forceinline__ uint4 pack8(const float* v){
  uint4 r;
  r.x=(u32)f2bf(v[0])|((u32)f2bf(v[1])<<16);
  r.y=(u32)f2bf(v[2])|((u32)f2bf(v[3])<<16);
  r.z=(u32)f2bf(v[4])|((u32)f2bf(v[5])<<16);
  r.w=(u32)f2bf(v[6])|((u32)f2bf(v[7])<<16);
  return r;
}

// unpack 8 bf16 + affine + relu
static __device__ __forceinline__ void unp8_aff(uint4 r, const float* A, const float* C, int cb, float* o){
  o[0]=fmaxf(fmaf(bf2f(r.x&0xffffu),A[cb+0],C[cb+0]),0.f);
  o[1]=fmaxf(fmaf(bf2f(r.x>>16)    ,A[cb+1],C[cb+1]),0.f);
  o[2]=fmaxf(fmaf(bf2f(r.y&0xffffu),A[cb+2],C[cb+2]),0.f);
  o[3]=fmaxf(fmaf(bf2f(r.y>>16)    ,A[cb+3],C[cb+3]),0.f);
  o[4]=fmaxf(fmaf(bf2f(r.z&0xffffu),A[cb+4],C[cb+4]),0.f);
  o[5]=fmaxf(fmaf(bf2f(r.z>>16)    ,A[cb+5],C[cb+5]),0.f);
  o[6]=fmaxf(fmaf(bf2f(r.w&0xffffu),A[cb+6],C[cb+6]),0.f);
  o[7]=fmaxf(fmaf(bf2f(r.w>>16)    ,A[cb+7],C[cb+7]),0.f);
}

// DPP helpers
template<int CTRL, int RMASK>
static __device__ __forceinline__ u32 dppmax(u32 m){
  u32 t=(u32)__builtin_amdgcn_update_dpp(0, (int)m, CTRL, RMASK, 0xf, false);
  return t>m ? t : m;
}
template<int CTRL, int RMASK>
static __device__ __forceinline__ float dppadd1(float v){
  float t=__uint_as_float((u32)__builtin_amdgcn_update_dpp(0,(int)__float_as_uint(v),CTRL,RMASK,0xf,false));
  return v+t;
}
static __device__ __forceinline__ float dppsum(float v){
  v=dppadd1<0x111,0xf>(v);
  v=dppadd1<0x112,0xf>(v);
  v=dppadd1<0x114,0xf>(v);
  v=dppadd1<0x118,0xf>(v);
  v=dppadd1<0x142,0xa>(v);
  v=dppadd1<0x143,0xc>(v);
  return v;
}
static __device__ __forceinline__ float rl63(float v){
  return __uint_as_float((u32)__builtin_amdgcn_readlane((int)__float_as_uint(v),63));
}

// ---------------- FPS: 256 threads (4 waves, 1/SIMD), 16 points/thread ----------------
__global__ __launch_bounds__(256) void k_fps(const float* __restrict__ xyz,
                                             float* __restrict__ fpsq, float* __restrict__ outx){
  __shared__ float X[NN], Y[NN], Z[NN];
  __shared__ float QX[SS], QY[SS], QZ[SS];
  __shared__ u64 red[2][4];
  int b=blockIdx.x, t=threadIdx.x;
  const float* xb=xyz+(size_t)b*3*NN;
  for (int i=t;i<NN;i+=256){ X[i]=xb[i]; Y[i]=xb[NN+i]; Z[i]=xb[2*NN+i]; }
  __syncthreads();
  f32x2 px[8],py[8],pz[8],dd[8];
  #pragma unroll
  for (int k=0;k<8;k++){
    int i=t*16+2*k;
    px[k].x=X[i]; px[k].y=X[i+1];
    py[k].x=Y[i]; py[k].y=Y[i+1];
    pz[k].x=Z[i]; pz[k].y=Z[i+1];
    dd[k].x=1e10f; dd[k].y=1e10f;
  }
  int wv=t>>6, ln=t&63;
  int far=0;
  for (int s=0;s<SS;s++){
    float fx=X[far], fy=Y[far], fz=Z[far];
    if (t==0){ QX[s]=fx; QY[s]=fy; QZ[s]=fz; }
    f32x2 nfx, nfy, nfz;
    nfx.x=-fx; nfx.y=-fx; nfy.x=-fy; nfy.y=-fy; nfz.x=-fz; nfz.y=-fz;
    #pragma unroll
    for (int k=0;k<8;k++){
      f32x2 dx=pk_add(px[k],nfx);      // == px - fx (IEEE: a-b = a+(-b))
      f32x2 xx=pk_mul(dx,dx);
      f32x2 dy=pk_add(py[k],nfy);
      f32x2 yy=pk_mul(dy,dy);
      f32x2 dz=pk_add(pz[k],nfz);
      f32x2 zz=pk_mul(dz,dz);
      f32x2 s1=pk_add(xx,yy);
      f32x2 d2=pk_add(s1,zz);          // ((dx^2+dy^2)+dz^2), ref order
      dd[k].x=fminf(dd[k].x,d2.x);
      dd[k].y=fminf(dd[k].y,d2.y);
    }
    // thread-local max tree over 16 values (dd >= 0 -> uint compare == float compare)
    float l0=fmaxf(dd[0].x,dd[0].y), l1=fmaxf(dd[1].x,dd[1].y);
    float l2=fmaxf(dd[2].x,dd[2].y), l3=fmaxf(dd[3].x,dd[3].y);
    float l4=fmaxf(dd[4].x,dd[4].y), l5=fmaxf(dd[5].x,dd[5].y);
    float l6=fmaxf(dd[6].x,dd[6].y), l7=fmaxf(dd[7].x,dd[7].y);
    float m01=fmaxf(l0,l1), m23=fmaxf(l2,l3), m45=fmaxf(l4,l5), m67=fmaxf(l6,l7);
    u32 m=__float_as_uint(fmaxf(fmaxf(m01,m23),fmaxf(m45,m67)));
    // row-wise DPP reduce, then SALU combine of the 4 row maxima
    m=dppmax<0x111,0xf>(m);
    m=dppmax<0x112,0xf>(m);
    m=dppmax<0x114,0xf>(m);
    m=dppmax<0x118,0xf>(m);
    u32 r15=(u32)__builtin_amdgcn_readlane((int)m,15);
    u32 r31=(u32)__builtin_amdgcn_readlane((int)m,31);
    u32 r47=(u32)__builtin_amdgcn_readlane((int)m,47);
    u32 r63=(u32)__builtin_amdgcn_readlane((int)m,63);
    u32 ab = r15>r31 ? r15 : r31;
    u32 cd = r47>r63 ? r47 : r63;
    u32 wmax = ab>cd ? ab : cd;
    // lowest local element achieving wmax (descending scan -> lowest wins)
    int lj=16;
    if (__float_as_uint(dd[7].y)==wmax) lj=15;
    if (__float_as_uint(dd[7].x)==wmax) lj=14;
    if (__float_as_uint(dd[6].y)==wmax) lj=13;
    if (__float_as_uint(dd[6].x)==wmax) lj=12;
    if (__float_as_uint(dd[5].y)==wmax) lj=11;
    if (__float_as_uint(dd[5].x)==wmax) lj=10;
    if (__float_as_uint(dd[4].y)==wmax) lj=9;
    if (__float_as_uint(dd[4].x)==wmax) lj=8;
    if (__float_as_uint(dd[3].y)==wmax) lj=7;
    if (__float_as_uint(dd[3].x)==wmax) lj=6;
    if (__float_as_uint(dd[2].y)==wmax) lj=5;
    if (__float_as_uint(dd[2].x)==wmax) lj=4;
    if (__float_as_uint(dd[1].y)==wmax) lj=3;
    if (__float_as_uint(dd[1].x)==wmax) lj=2;
    if (__float_as_uint(dd[0].y)==wmax) lj=1;
    if (__float_as_uint(dd[0].x)==wmax) lj=0;
    u64 ball=__ballot(lj<16);
    u32 wl=(u32)__builtin_ctzll(ball);            // lowest lane == lowest index (contiguous)
    int gi=t*16+lj;
    u32 widx=(u32)__builtin_amdgcn_readlane(gi,wl);
    int pb=s&1;
    if (ln==0) red[pb][wv]=((u64)wmax<<32)|(u32)(4095u-widx);
    __syncthreads();
    // keys are positive finite doubles -> f64 max == u64 max
    const double* rd=(const double*)&red[pb][0];
    double g=fmax(fmax(rd[0],rd[1]),fmax(rd[2],rd[3]));
    far=4095-(int)(__double_as_longlong(g)&0xFFFull);
  }
  __syncthreads();
  for (int i=t;i<SS;i+=256){
    float qx=QX[i], qy=QY[i], qz=QZ[i];
    float* q=&fpsq[((size_t)b*SS+i)*3]; q[0]=qx; q[1]=qy; q[2]=qz;
    outx[b*3*SS+i]=qx; outx[b*3*SS+SS+i]=qy; outx[b*3*SS+2*SS+i]=qz;
  }
}

// ---------------- KNN (blocks 0-1023) + featT/lwbf (1024-1279) + prep (1280) ----------------
#define KSTR 68
__global__ __launch_bounds__(512) void k_knnft(const float* __restrict__ xyz, const float* __restrict__ fpsq,
    int* __restrict__ kidx,
    const float* __restrict__ f, float* __restrict__ ft,
    const float* __restrict__ ww0,const float* __restrict__ ww1,const float* __restrict__ ww2,
    const float* __restrict__ lw, u16* __restrict__ lwbf,
    float* __restrict__ wt0,float* __restrict__ wt1,float* __restrict__ wt2,
    float* __restrict__ statsf){
  extern __shared__ char smem[];
  int blk=blockIdx.x; int t=threadIdx.x;
  if (blk>=1024){
    if (blk==1280){
      for (int i=t;i<1024;i+=512) statsf[i]=0.f;
      for (int i=t;i<8*3;i+=512){ int o=i/3,k=i%3; wt0[k*8+o]=ww0[i]; }
      for (int i=t;i<8*8;i+=512){ int o=i>>3,k=i&7; wt1[k*8+o]=ww1[i]; }
      for (int i=t;i<16*8;i+=512){ int o=i>>3,k=i&7; wt2[k*16+o]=ww2[i]; }
      return;
    }
    // lwbf chunk (1024 elems per block)
    {
      int base2=(blk-1024)*1024;
      for (int i=t;i<1024;i+=512) lwbf[base2+i]=f2bf(lw[base2+i]);
    }
    // feature transpose: 2 tiles per block
    float (*tile)[64][65]=(float(*)[64][65])smem;
    int sub=t>>8, tt=t&255;
    int tileIdx=(blk-1024)*2+sub;
    int b=tileIdx>>6; int n0=(tileIdx&63)*64;
    const float* fb=f+(size_t)b*64*NN;
    int c0=tt>>6, nn=tt&63;
    #pragma unroll
    for (int it=0;it<16;it++){ int c=c0+it*4; tile[sub][c][nn]=fb[(size_t)c*NN+n0+nn]; }
    __syncthreads();
    int cc=tt&63, n1=tt>>6;
    float* fo=ft+((size_t)b*NN+n0)*64;
    #pragma unroll
    for (int it=0;it<16;it++){ int n=n1+it*4; fo[(size_t)n*64+cc]=tile[sub][cc][n]; }
    return;
  }
  float* xs=(float*)smem;
  float* ys=xs+64*KSTR;
  float* zs=ys+64*KSTR;
  float* pn=zs+64*KSTR;
  int b=blk>>7; int s0=(blk&127)*8;
  const float* xb=xyz+(size_t)b*3*NN;
  for (int i=t;i<NN;i+=512){
    float x=xb[i],y=xb[NN+i],z=xb[2*NN+i];
    int slot=(i>>6)*KSTR+(i&63);
    xs[slot]=x; ys[slot]=y; zs[slot]=z;
    pn[slot]=__fadd_rn(__fadd_rn(__fmul_rn(x,x),__fmul_rn(y,y)),__fmul_rn(z,z));
  }
  __syncthreads();
  int wv=t>>6, ln=t&63;
  int s=s0+wv;
  const float* q=&fpsq[((size_t)b*SS+s)*3];
  float qx=q[0],qy=q[1],qz=q[2];
  float qn=__fadd_rn(__fadd_rn(__fmul_rn(qx,qx),__fmul_rn(qy,qy)),__fmul_rn(qz,qz));
  f32x2 qxx,qyy,qzz,qnn,mtwo;
  qxx.x=qx;qxx.y=qx; qyy.x=qy;qyy.y=qy; qzz.x=qz;qzz.y=qz; qnn.x=qn;qnn.y=qn;
  mtwo.x=-2.f; mtwo.y=-2.f;
  const float4* Xp=(const float4*)(xs+ln*KSTR);
  const float4* Yp=(const float4*)(ys+ln*KSTR);
  const float4* Zp=(const float4*)(zs+ln*KSTR);
  const float4* Pp=(const float4*)(pn+ln*KSTR);
  int base=ln*64;
  u64 v[64];
  #pragma unroll
  for (int g=0;g<16;g++){
    float4 x4=Xp[g], y4=Yp[g], z4=Zp[g], p4=Pp[g];
    #pragma unroll
    for (int h=0;h<2;h++){
      f32x2 px2,py2,pz2,pn2;
      if (h==0){ px2.x=x4.x;px2.y=x4.y; py2.x=y4.x;py2.y=y4.y; pz2.x=z4.x;pz2.y=z4.y; pn2.x=p4.x;pn2.y=p4.y; }
      else     { px2.x=x4.z;px2.y=x4.w; py2.x=y4.z;py2.y=y4.w; pz2.x=z4.z;pz2.y=z4.w; pn2.x=p4.z;pn2.y=p4.w; }
      f32x2 m1=pk_mul(qxx,px2);
      f32x2 mm=pk_mul(qyy,py2);
      f32x2 a1=pk_add(m1,mm);
      f32x2 m3=pk_mul(qzz,pz2);
      f32x2 dt=pk_add(a1,m3);
      f32x2 qp=pk_add(qnn,pn2);
      f32x2 nd=pk_mul(dt,mtwo);
      f32x2 d2=pk_add(qp,nd);
      #pragma unroll
      for (int e=0;e<2;e++){
        u32 bu=__float_as_uint(e?d2.y:d2.x);
        bu = ((int)bu<0)? ~bu : (bu|0x80000000u);
        v[g*4+h*2+e]=((u64)bu<<32)|(u32)(base+g*4+h*2+e);
      }
    }
  }
  u64 cand[8];
  #pragma unroll
  for (int gg=0;gg<8;gg++){
    u64 c=v[gg*8];
    #pragma unroll
    for (int j=1;j<8;j++){ u64 x=v[gg*8+j]; c = x<c?x:c; }
    cand[gg]=c;
  }
  u64 best=cand[0];
  #pragma unroll
  for (int gg=1;gg<8;gg++){ u64 x=cand[gg]; best = x<best?x:best; }
  int my=0;
  #pragma unroll 1
  for (int r=0;r<KK;r++){
    u64 w=best;
    #pragma unroll
    for (int m=1;m<64;m<<=1){ u64 o=__shfl_xor(w,m,64); w = o<w?o:w; }
    if (ln==r) my=(int)(w&0xFFFull);
    if (best==w){
      #pragma unroll
      for (int gg=0;gg<8;gg++){
        if (cand[gg]==w){
          u64 c=~0ull;
          #pragma unroll
          for (int j=0;j<8;j++){ u64 x=v[gg*8+j]; x = x>w ? x : ~0ull; c = x<c?x:c; }
          cand[gg]=c;
        }
      }
      u64 nb=cand[0];
      #pragma unroll
      for (int gg=1;gg<8;gg++){ u64 x=cand[gg]; nb = x<nb?x:nb; }
      best=nb;
    }
  }
  if (ln<KK) kidx[(((size_t)b*SS+s)<<5)+ln]=my;
}

// ---------------- layer 0 (MFMA): gather + 67->64 via C-operand + wnet 3->8 (+stats) ----------------
__global__ __launch_bounds__(256) void k_l0(const float* __restrict__ xyz, const float* __restrict__ ft,
    const float* __restrict__ fpsq, const int* __restrict__ kidx,
    const float* __restrict__ w0, const float* __restrict__ wt0,
    u16* __restrict__ y0, float* __restrict__ wl0, float* __restrict__ statsf){
  __shared__ u16 Bw[64*72];
  __shared__ float gt[256][4];
  __shared__ int jt[256];
  __shared__ float pS[4][64], pQ[4][64];
  __shared__ float pWS[4][8], pWQ[4][8];
  int t=threadIdx.x; int wv=t>>6, ln=t&63;
  int p=blockIdx.x*256+t;
  int b=p>>15;
  int site=p>>5;
  int j=kidx[p];
  const float* xb=xyz+(size_t)b*3*NN;
  const float* q=fpsq+(size_t)site*3;
  float gx=xb[j]-q[0], gy=xb[NN+j]-q[1], gz=xb[2*NN+j]-q[2];
  gt[t][0]=gx; gt[t][1]=gy; gt[t][2]=gz; gt[t][3]=0.f; jt[t]=j;
  for (int i=t;i<4096;i+=256){ int col=i>>6,k=i&63; Bw[col*72+k]=f2bf(w0[col*67+3+k]); }
  __syncthreads();
  float wxc[4],wyc[4],wzc[4];
  #pragma unroll
  for (int n=0;n<4;n++){
    int c=n*16+(ln&15);
    wxc[n]=w0[c*67+0]; wyc[n]=w0[c*67+1]; wzc[n]=w0[c*67+2];
  }
  float sS[4]={0,0,0,0}, sQ[4]={0,0,0,0};
  int base=wv*64;
  #pragma unroll 1
  for (int rs=0;rs<4;rs++){
    int lrow=base+rs*16+(ln&15);
    int jr=jt[lrow];
    const float* fp=ft+((size_t)b*NN+jr)*64 + (ln>>4)*8;
    float4 fa=*(const float4*)fp, fb4=*(const float4*)(fp+4);
    float4 fc=*(const float4*)(fp+32), fd=*(const float4*)(fp+36);
    float va[8]={fa.x,fa.y,fa.z,fa.w,fb4.x,fb4.y,fb4.z,fb4.w};
    float vb[8]={fc.x,fc.y,fc.z,fc.w,fd.x,fd.y,fd.z,fd.w};
    bf16x8 a0,a1;
    #pragma unroll
    for (int e=0;e<8;e++){ ((u16*)&a0)[e]=(short)f2bf(va[e]); ((u16*)&a1)[e]=(short)f2bf(vb[e]); }
    int r0=base+rs*16+(ln>>4)*4;
    float4 g0v4=*(const float4*)&gt[r0+0][0];
    float4 g1v4=*(const float4*)&gt[r0+1][0];
    float4 g2v4=*(const float4*)&gt[r0+2][0];
    float4 g3v4=*(const float4*)&gt[r0+3][0];
    float gxr[4]={g0v4.x,g1v4.x,g2v4.x,g3v4.x};
    float gyr[4]={g0v4.y,g1v4.y,g2v4.y,g3v4.y};
    float gzr[4]={g0v4.z,g1v4.z,g2v4.z,g3v4.z};
    int pr=blockIdx.x*256+base+rs*16;
    #pragma unroll
    for (int n=0;n<4;n++){
      const u16* bp=&Bw[(size_t)(n*16+(ln&15))*72 + (ln>>4)*8];
      bf16x8 b0=*(const bf16x8*)bp;
      bf16x8 b1=*(const bf16x8*)(bp+32);
      f32x4 acc;
      #pragma unroll
      for (int i=0;i<4;i++) acc[i]=fmaf(gxr[i],wxc[n],fmaf(gyr[i],wyc[n],gzr[i]*wzc[n]));
      acc=mfma16(a0,b0,acc);
      acc=mfma16(a1,b1,acc);
      #pragma unroll
      for (int i=0;i<4;i++){
        int row=(ln>>4)*4+i;
        y0[(size_t)(pr+row)*64 + n*16 + (ln&15)]=f2bf(acc[i]);
        sS[n]+=acc[i]; sQ[n]=fmaf(acc[i],acc[i],sQ[n]);
      }
    }
  }
  #pragma unroll
  for (int n=0;n<4;n++){
    sS[n]+=__shfl_xor(sS[n],16,64); sS[n]+=__shfl_xor(sS[n],32,64);
    sQ[n]+=__shfl_xor(sQ[n],16,64); sQ[n]+=__shfl_xor(sQ[n],32,64);
  }
  if (ln<16){
    #pragma unroll
    for (int n=0;n<4;n++){ pS[wv][n*16+ln]=sS[n]; pQ[wv][n*16+ln]=sQ[n]; }
  }
  float wa[8];
  #pragma unroll
  for (int o=0;o<8;o++) wa[o]=fmaf(gx,wt0[o],fmaf(gy,wt0[8+o],gz*wt0[16+o]));
  float4* wr=(float4*)(wl0+(size_t)p*8);
  wr[0]=make_float4(wa[0],wa[1],wa[2],wa[3]);
  wr[1]=make_float4(wa[4],wa[5],wa[6],wa[7]);
  float wS[8],wQ[8];
  #pragma unroll
  for (int o=0;o<8;o++){
    wS[o]=rl63(dppsum(wa[o]));
    wQ[o]=rl63(dppsum(wa[o]*wa[o]));
  }
  if (ln==0){
    #pragma unroll
    for (int o=0;o<8;o++){ pWS[wv][o]=wS[o]; pWQ[wv][o]=wQ[o]; }
  }
  __syncthreads();
  if (t<64){
    float S=pS[0][t]+pS[1][t]+pS[2][t]+pS[3][t];
    float Q=pQ[0][t]+pQ[1][t]+pQ[2][t]+pQ[3][t];
    atomicAdd(&statsf[2*(ST_Y0+t)],S); atomicAdd(&statsf[2*(ST_Y0+t)+1],Q);
  } else if (t<72){
    int c=t-64;
    float S=pWS[0][c]+pWS[1][c]+pWS[2][c]+pWS[3][c];
    float Q=pWQ[0][c]+pWQ[1][c]+pWQ[2][c]+pWQ[3][c];
    atomicAdd(&statsf[2*(ST_W0+c)],S); atomicAdd(&statsf[2*(ST_W0+c)+1],Q);
  }
}

// ---------------- layer 1 (MFMA): BN0+relu -> 64->64 ; wnet 8->8 (+stats from acc) ----------------
__global__ __launch_bounds__(256) void k_l1(const u16* __restrict__ y0, const float* __restrict__ wl0,
    const float* __restrict__ w1, const float* __restrict__ wt1,
    const float* __restrict__ statsf,
    const float* __restrict__ g0v, const float* __restrict__ be0v,
    const float* __restrict__ wg0v, const float* __restrict__ wbe0v,
    u16* __restrict__ y1, float* __restrict__ wl1, float* __restrict__ statso){
  __shared__ float A0[64],C0[64],AW[8],CW[8];
  __shared__ u16 Bw[64*72];
  __shared__ u16 Atile[4][16*72];
  __shared__ float pS[4][64], pQ[4][64];
  __shared__ float pWS[4][8], pWQ[4][8];
  int t=threadIdx.x; int wv=t>>6, ln=t&63;
  if (t<64){
    float sm=statsf[(ST_Y0+t)*2], sq=statsf[(ST_Y0+t)*2+1];
    float mean=sm*(1.f/PP), var=fmaxf(sq*(1.f/PP)-mean*mean,0.f);
    float a=g0v[t]*rsqrtf(var+1e-5f); A0[t]=a; C0[t]=be0v[t]-mean*a;
  } else if (t<72){
    int c=t-64;
    float sm=statsf[(ST_W0+c)*2], sq=statsf[(ST_W0+c)*2+1];
    float mean=sm*(1.f/PP), var=fmaxf(sq*(1.f/PP)-mean*mean,0.f);
    float a=wg0v[c]*rsqrtf(var+1e-5f); AW[c]=a; CW[c]=wbe0v[c]-mean*a;
  }
  for (int i=t;i<4096;i+=256){ Bw[(i>>6)*72+(i&63)]=f2bf(w1[i]); }
  __syncthreads();
  bf16x8 bfr[4][2];
  #pragma unroll
  for (int n=0;n<4;n++){
    const u16* bp=&Bw[(size_t)(n*16+(ln&15))*72 + (ln>>4)*8];
    bfr[n][0]=*(const bf16x8*)bp;
    bfr[n][1]=*(const bf16x8*)(bp+32);
  }
  float sS[4]={0,0,0,0}, sQ[4]={0,0,0,0};
  int p0=blockIdx.x*256 + wv*64;
  u16* At=Atile[wv];
  #pragma unroll 1
  for (int rs=0;rs<4;rs++){
    int pr=p0+rs*16;
    {
      const u16* ysrc=y0+(size_t)pr*64 + ln*16;
      uint4 raw0=*(const uint4*)ysrc;
      uint4 raw1=*(const uint4*)(ysrc+8);
      int row=ln>>2, cb=(ln&3)*16;
      float tmp[8];
      unp8_aff(raw0,A0,C0,cb,tmp);
      *(uint4*)&At[row*72+cb]=pack8(tmp);
      unp8_aff(raw1,A0,C0,cb+8,tmp);
      *(uint4*)&At[row*72+cb+8]=pack8(tmp);
    }
    const u16* ap=&At[(ln&15)*72 + (ln>>4)*8];
    bf16x8 a0=*(const bf16x8*)ap;
    bf16x8 a1=*(const bf16x8*)(ap+32);
    #pragma unroll
    for (int n=0;n<4;n++){
      f32x4 acc={0.f,0.f,0.f,0.f};
      acc=mfma16(a0,bfr[n][0],acc);
      acc=mfma16(a1,bfr[n][1],acc);
      #pragma unroll
      for (int i=0;i<4;i++){
        int row=(ln>>4)*4+i;
        y1[(size_t)(pr+row)*64 + n*16 + (ln&15)]=f2bf(acc[i]);
        sS[n]+=acc[i]; sQ[n]=fmaf(acc[i],acc[i],sQ[n]);
      }
    }
  }
  #pragma unroll
  for (int n=0;n<4;n++){
    sS[n]+=__shfl_xor(sS[n],16,64); sS[n]+=__shfl_xor(sS[n],32,64);
    sQ[n]+=__shfl_xor(sQ[n],16,64); sQ[n]+=__shfl_xor(sQ[n],32,64);
  }
  if (ln<16){
    #pragma unroll
    for (int n=0;n<4;n++){ pS[wv][n*16+ln]=sS[n]; pQ[wv][n*16+ln]=sQ[n]; }
  }
  int p=blockIdx.x*256+t;
  const float4* wvp=(const float4*)(wl0+(size_t)p*8);
  float4 v0=wvp[0], v1=wvp[1];
  float wi[8]={v0.x,v0.y,v0.z,v0.w,v1.x,v1.y,v1.z,v1.w};
  float wo[8];
  #pragma unroll
  for (int o=0;o<8;o++) wo[o]=0.f;
  #pragma unroll
  for (int k=0;k<8;k++){
    float xr=fmaxf(fmaf(wi[k],AW[k],CW[k]),0.f);
    #pragma unroll
    for (int o=0;o<8;o++) wo[o]=fmaf(xr,wt1[k*8+o],wo[o]);
  }
  float4* wr=(float4*)(wl1+(size_t)p*8);
  wr[0]=make_float4(wo[0],wo[1],wo[2],wo[3]);
  wr[1]=make_float4(wo[4],wo[5],wo[6],wo[7]);
  float wS[8],wQ[8];
  #pragma unroll
  for (int o=0;o<8;o++){
    wS[o]=rl63(dppsum(wo[o]));
    wQ[o]=rl63(dppsum(wo[o]*wo[o]));
  }
  if (ln==0){
    #pragma unroll
    for (int o=0;o<8;o++){ pWS[wv][o]=wS[o]; pWQ[wv][o]=wQ[o]; }
  }
  __syncthreads();
  if (t<64){
    float S=pS[0][t]+pS[1][t]+pS[2][t]+pS[3][t];
    float Q=pQ[0][t]+pQ[1][t]+pQ[2][t]+pQ[3][t];
    atomicAdd(&statso[2*(ST_Y1+t)],S); atomicAdd(&statso[2*(ST_Y1+t)+1],Q);
  } else if (t<72){
    int c=t-64;
    float S=pWS[0][c]+pWS[1][c]+pWS[2][c]+pWS[3][c];
    float Q=pWQ[0][c]+pWQ[1][c]+pWQ[2][c]+pWQ[3][c];
    atomicAdd(&statso[2*(ST_W1+c)],S); atomicAdd(&statso[2*(ST_W1+c)+1],Q);
  }
}

// ---------------- layer 2 (MFMA): BN1+relu -> 64->128 ; wnet 8->16 (+stats from acc) ----------------
__global__ __launch_bounds__(256) void k_l2(const u16* __restrict__ y1, const float* __restrict__ wl1,
    const float* __restrict__ w2, const float* __restrict__ wt2,
    const float* __restrict__ statsf,
    const float* __restrict__ g1v, const float* __restrict__ be1v,
    const float* __restrict__ wg1v, const float* __restrict__ wbe1v,
    u16* __restrict__ y2, float* __restrict__ wl2, float* __restrict__ statso){
  __shared__ float A1[64],C1[64],AW[8],CW[8];
  __shared__ u16 Bw[128*72];
  __shared__ u16 Atile[4][16*72];
  __shared__ float pS[4][128], pQ[4][128];
  __shared__ float pWS[4][16], pWQ[4][16];
  int t=threadIdx.x; int wv=t>>6, ln=t&63;
  if (t<64){
    float sm=statsf[(ST_Y1+t)*2], sq=statsf[(ST_Y1+t)*2+1];
    float mean=sm*(1.f/PP), var=fmaxf(sq*(1.f/PP)-mean*mean,0.f);
    float a=g1v[t]*rsqrtf(var+1e-5f); A1[t]=a; C1[t]=be1v[t]-mean*a;
  } else if (t<72){
    int c=t-64;
    float sm=statsf[(ST_W1+c)*2], sq=statsf[(ST_W1+c)*2+1];
    float mean=sm*(1.f/PP), var=fmaxf(sq*(1.f/PP)-mean*mean,0.f);
    float a=wg1v[c]*rsqrtf(var+1e-5f); AW[c]=a; CW[c]=wbe1v[c]-mean*a;
  }
  for (int i=t;i<8192;i+=256){ Bw[(i>>6)*72+(i&63)]=f2bf(w2[i]); }
  __syncthreads();
  float sS[8]={0,0,0,0,0,0,0,0}, sQ[8]={0,0,0,0,0,0,0,0};
  int p0=blockIdx.x*256 + wv*64;
  u16* At=Atile[wv];
  #pragma unroll 1
  for (int rs=0;rs<4;rs++){
    int pr=p0+rs*16;
    {
      const u16* ysrc=y1+(size_t)pr*64 + ln*16;
      uint4 raw0=*(const uint4*)ysrc;
      uint4 raw1=*(const uint4*)(ysrc+8);
      int row=ln>>2, cb=(ln&3)*16;
      float tmp[8];
      unp8_aff(raw0,A1,C1,cb,tmp);
      *(uint4*)&At[row*72+cb]=pack8(tmp);
      unp8_aff(raw1,A1,C1,cb+8,tmp);
      *(uint4*)&At[row*72+cb+8]=pack8(tmp);
    }
    const u16* ap=&At[(ln&15)*72 + (ln>>4)*8];
    bf16x8 a0=*(const bf16x8*)ap;
    bf16x8 a1=*(const bf16x8*)(ap+32);
    #pragma unroll
    for (int n=0;n<8;n++){
      const u16* bp=&Bw[(size_t)(n*16+(ln&15))*72 + (ln>>4)*8];
      bf16x8 b0=*(const bf16x8*)bp;
      bf16x8 b1=*(const bf16x8*)(bp+32);
      f32x4 acc={0.f,0.f,0.f,0.f};
      acc=mfma16(a0,b0,acc);
      acc=mfma16(a1,b1,acc);
      #pragma unroll
      for (int i=0;i<4;i++){
        int row=(ln>>4)*4+i;
        y2[(size_t)(pr+row)*128 + n*16 + (ln&15)]=f2bf(acc[i]);
        sS[n]+=acc[i]; sQ[n]=fmaf(acc[i],acc[i],sQ[n]);
      }
    }
  }
  #pragma unroll
  for (int n=0;n<8;n++){
    sS[n]+=__shfl_xor(sS[n],16,64); sS[n]+=__shfl_xor(sS[n],32,64);
    sQ[n]+=__shfl_xor(sQ[n],16,64); sQ[n]+=__shfl_xor(sQ[n],32,64);
  }
  if (ln<16){
    #pragma unroll
    for (int n=0;n<8;n++){ pS[wv][n*16+ln]=sS[n]; pQ[wv][n*16+ln]=sQ[n]; }
  }
  int p=blockIdx.x*256+t;
  const float4* wvp=(const float4*)(wl1+(size_t)p*8);
  float4 v0=wvp[0], v1=wvp[1];
  float wi[8]={v0.x,v0.y,v0.z,v0.w,v1.x,v1.y,v1.z,v1.w};
  float wo[16];
  #pragma unroll
  for (int o=0;o<16;o++) wo[o]=0.f;
  #pragma unroll
  for (int k=0;k<8;k++){
    float xr=fmaxf(fmaf(wi[k],AW[k],CW[k]),0.f);
    #pragma unroll
    for (int o=0;o<16;o++) wo[o]=fmaf(xr,wt2[k*16+o],wo[o]);
  }
  float4* wr=(float4*)(wl2+(size_t)p*16);
  wr[0]=make_float4(wo[0],wo[1],wo[2],wo[3]);
  wr[1]=make_float4(wo[4],wo[5],wo[6],wo[7]);
  wr[2]=make_float4(wo[8],wo[9],wo[10],wo[11]);
  wr[3]=make_float4(wo[12],wo[13],wo[14],wo[15]);
  float wS[16],wQ[16];
  #pragma unroll
  for (int o=0;o<16;o++){
    wS[o]=rl63(dppsum(wo[o]));
    wQ[o]=rl63(dppsum(wo[o]*wo[o]));
  }
  if (ln==0){
    #pragma unroll
    for (int o=0;o<16;o++){ pWS[wv][o]=wS[o]; pWQ[wv][o]=wQ[o]; }
  }
  __syncthreads();
  if (t<128){
    float S=pS[0][t]+pS[1][t]+pS[2][t]+pS[3][t];
    float Q=pQ[0][t]+pQ[1][t]+pQ[2][t]+pQ[3][t];
    atomicAdd(&statso[2*(ST_Y2+t)],S); atomicAdd(&statso[2*(ST_Y2+t)+1],Q);
  } else if (t<144){
    int c=t-128;
    float S=pWS[0][c]+pWS[1][c]+pWS[2][c]+pWS[3][c];
    float Q=pWQ[0][c]+pWQ[1][c]+pWQ[2][c]+pWQ[3][c];
    atomicAdd(&statso[2*(ST_W2+c)],S); atomicAdd(&statso[2*(ST_W2+c)+1],Q);
  }
}

// ---------------- fused agg+lin: pool 16 sites to LDS, then MFMA vs lwbf (+lin stats) ----------------
__global__ __launch_bounds__(256) void k_agglin(const u16* __restrict__ y2, const float* __restrict__ wl2,
    const float* __restrict__ statsf,
    const float* __restrict__ g2v, const float* __restrict__ be2v,
    const float* __restrict__ wg2v, const float* __restrict__ wbe2v,
    const u16* __restrict__ lwbf, float* __restrict__ lin, float* __restrict__ outst){
  __shared__ float A2[128],C2[128],AW[16],CW[16];
  __shared__ float wt[32*16];
  __shared__ u16 aggt[16][2056];
  __shared__ float pS[4][32], pQ[4][32];
  int t=threadIdx.x; int wv=t>>6, ln=t&63;
  int s0=blockIdx.x*16;
  if (t<128){
    float sm=statsf[(ST_Y2+t)*2], sq=statsf[(ST_Y2+t)*2+1];
    float mean=sm*(1.f/PP), var=fmaxf(sq*(1.f/PP)-mean*mean,0.f);
    float a=g2v[t]*rsqrtf(var+1e-5f); A2[t]=a; C2[t]=be2v[t]-mean*a;
  } else if (t<144){
    int c=t-128;
    float sm=statsf[(ST_W2+c)*2], sq=statsf[(ST_W2+c)*2+1];
    float mean=sm*(1.f/PP), var=fmaxf(sq*(1.f/PP)-mean*mean,0.f);
    float a=wg2v[c]*rsqrtf(var+1e-5f); AW[c]=a; CW[c]=wbe2v[c]-mean*a;
  }
  __syncthreads();
  int d=t>>1, cb=(t&1)*8;
  float a2d=A2[d], c2d=C2[d];
  #pragma unroll 1
  for (int si=0; si<16; si++){
    int site=s0+si;
    #pragma unroll
    for (int it=0; it<2; it++){
      int i=t+it*256;
      float x=wl2[(size_t)site*512+i]; int c=i&15;
      wt[i]=fmaxf(fmaf(x,AW[c],CW[c]),0.f);
    }
    __syncthreads();
    float acc[8];
    #pragma unroll
    for (int e=0;e<8;e++) acc[e]=0.f;
    const u16* ys=y2+(size_t)site*4096;
    #pragma unroll 4
    for (int kq=0;kq<32;kq++){
      float nv=fmaxf(fmaf(bf2f((u32)ys[kq*128+d]),a2d,c2d),0.f);
      #pragma unroll
      for (int e=0;e<8;e++) acc[e]=fmaf(nv,wt[kq*16+cb+e],acc[e]);
    }
    *(uint4*)&aggt[si][d*16+cb]=pack8(acc);
    __syncthreads();
  }
  // phase B: lin MFMA from LDS aggt
  const u16* arow=&aggt[ln&15][(ln>>4)*8];
  const u16* b0p=lwbf+(size_t)(wv*32+(ln&15))*2048 + (ln>>4)*8;
  const u16* b1p=b0p + (size_t)16*2048;
  f32x4 acc0={0.f,0.f,0.f,0.f}, acc1={0.f,0.f,0.f,0.f};
  #pragma unroll 4
  for (int kb=0;kb<2048;kb+=32){
    bf16x8 a=*(const bf16x8*)(arow+kb);
    bf16x8 b0=*(const bf16x8*)(b0p+kb);
    bf16x8 b1=*(const bf16x8*)(b1p+kb);
    acc0=mfma16(a,b0,acc0);
    acc1=mfma16(a,b1,acc1);
  }
  float sS0=0.f,sQ0=0.f,sS1=0.f,sQ1=0.f;
  #pragma unroll
  for (int i=0;i<4;i++){
    int row=(ln>>4)*4+i;
    lin[(size_t)(s0+row)*128 + wv*32 + (ln&15)]=acc0[i];
    lin[(size_t)(s0+row)*128 + wv*32 + 16 + (ln&15)]=acc1[i];
    sS0+=acc0[i]; sQ0=fmaf(acc0[i],acc0[i],sQ0);
    sS1+=acc1[i]; sQ1=fmaf(acc1[i],acc1[i],sQ1);
  }
  sS0+=__shfl_xor(sS0,16,64); sS0+=__shfl_xor(sS0,32,64);
  sQ0+=__shfl_xor(sQ0,16,64); sQ0+=__shfl_xor(sQ0,32,64);
  sS1+=__shfl_xor(sS1,16,64); sS1+=__shfl_xor(sS1,32,64);
  sQ1+=__shfl_xor(sQ1,16,64); sQ1+=__shfl_xor(sQ1,32,64);
  if (ln<16){ pS[wv][ln]=sS0; pS[wv][16+ln]=sS1; pQ[wv][ln]=sQ0; pQ[wv][16+ln]=sQ1; }
  __syncthreads();
  if (t<128){
    float S=pS[t>>5][t&31], Q=pQ[t>>5][t&31];
    atomicAdd(&outst[2*t],S); atomicAdd(&outst[2*t+1],Q);
  }
}

// ---------------- final BN + relu + transpose -> out [B,128,S] ----------------
__global__ __launch_bounds__(256) void k_out(const float* __restrict__ lin, const float* __restrict__ statsf,
    const float* __restrict__ lg, const float* __restrict__ lbe, float* __restrict__ outf){
  int t=blockIdx.x*256+threadIdx.x;
  int s4=(t&255)*4; int o=(t>>8)&127; int b=t>>15;
  float sm=statsf[(ST_LIN+o)*2], sq=statsf[(ST_LIN+o)*2+1];
  float mean=sm*(1.f/8192.f), var=fmaxf(sq*(1.f/8192.f)-mean*mean,0.f);
  float a=lg[o]*rsqrtf(var+1e-5f), cc=lbe[o]-mean*a;
  float v0=lin[((size_t)b*SS+s4+0)*128+o];
  float v1=lin[((size_t)b*SS+s4+1)*128+o];
  float v2=lin[((size_t)b*SS+s4+2)*128+o];
  float v3=lin[((size_t)b*SS+s4+3)*128+o];
  float4 r=make_float4(fmaxf(fmaf(v0,a,cc),0.f),fmaxf(fmaf(v1,a,cc),0.f),
                       fmaxf(fmaf(v2,a,cc),0.f),fmaxf(fmaf(v3,a,cc),0.f));
  *(float4*)(outf+((size_t)b*128+o)*SS+s4)=r;
}

extern "C" void kernel_launch(void* const* d_in, const int* in_sizes, int n_in,
                              void* d_out, int out_size, void* d_ws, size_t ws_size,
                              hipStream_t stream){
  (void)in_sizes;(void)n_in;(void)out_size;(void)ws_size;
  const float* xyz =(const float*)d_in[0];
  const float* feat=(const float*)d_in[1];
  const float* w0=(const float*)d_in[2];  const float* g0=(const float*)d_in[4];  const float* be0=(const float*)d_in[5];
  const float* w1=(const float*)d_in[6];  const float* g1=(const float*)d_in[8];  const float* be1=(const float*)d_in[9];
  const float* w2=(const float*)d_in[10]; const float* g2=(const float*)d_in[12]; const float* be2=(const float*)d_in[13];
  const float* ww0=(const float*)d_in[14]; const float* wg0=(const float*)d_in[16]; const float* wbe0=(const float*)d_in[17];
  const float* ww1=(const float*)d_in[18]; const float* wg1=(const float*)d_in[20]; const float* wbe1=(const float*)d_in[21];
  const float* ww2=(const float*)d_in[22]; const float* wg2=(const float*)d_in[24]; const float* wbe2=(const float*)d_in[25];
  const float* lw=(const float*)d_in[26]; const float* lg=(const float*)d_in[28]; const float* lbe=(const float*)d_in[29];
  float* out=(float*)d_out;
  char* ws=(char*)d_ws;

  size_t cur=0;
  auto alloc=[&](size_t bytes)->size_t{ cur=(cur+255)&~(size_t)255; size_t o=cur; cur+=bytes; return o; };
  size_t o_stats=alloc(4096);
  size_t o_wt0 =alloc(3*8*4);
  size_t o_wt1 =alloc(8*8*4);
  size_t o_wt2 =alloc(8*16*4);
  size_t o_lwbf=alloc((size_t)128*2048*2);
  size_t o_fpsq=alloc((size_t)BB*SS*3*4);
  size_t o_kidx=alloc((size_t)PP*4);
  size_t o_ft  =alloc((size_t)BB*NN*64*4);
  size_t o_y0  =alloc((size_t)PP*64*2);
  size_t o_y1  =alloc((size_t)PP*64*2);
  size_t o_y2  =alloc((size_t)PP*128*2);
  size_t o_wl0 =alloc((size_t)PP*8*4);
  size_t o_wl1 =alloc((size_t)PP*8*4);
  size_t o_wl2 =alloc((size_t)PP*16*4);
  size_t o_lin =alloc((size_t)8192*128*4);

  float* statsf=(float*)(ws+o_stats);
  float* wt0=(float*)(ws+o_wt0); float* wt1=(float*)(ws+o_wt1); float* wt2=(float*)(ws+o_wt2);
  u16* lwbf=(u16*)(ws+o_lwbf);
  float* fpsq=(float*)(ws+o_fpsq); int* kidx=(int*)(ws+o_kidx);
  float* ft=(float*)(ws+o_ft);
  u16* y0=(u16*)(ws+o_y0); u16* y1=(u16*)(ws+o_y1); u16* y2=(u16*)(ws+o_y2);
  float* wl0=(float*)(ws+o_wl0); float* wl1=(float*)(ws+o_wl1); float* wl2=(float*)(ws+o_wl2);
  float* lin=(float*)(ws+o_lin);

  size_t knn_smem = (size_t)4*64*KSTR*4;             // 69632 B (covers featT tiles too)

  hipLaunchKernelGGL(k_fps,dim3(BB),dim3(256),0,stream,xyz,fpsq,out);
  hipLaunchKernelGGL(k_knnft,dim3(1281),dim3(512),knn_smem,stream,xyz,fpsq,kidx,
                     feat,ft,ww0,ww1,ww2,lw,lwbf,wt0,wt1,wt2,statsf);
  hipLaunchKernelGGL(k_l0,dim3(PP/256),dim3(256),0,stream,xyz,ft,fpsq,kidx,w0,wt0,y0,wl0,statsf);
  hipLaunchKernelGGL(k_l1,dim3(PP/256),dim3(256),0,stream,y0,wl0,w1,wt1,statsf,g0,be0,wg0,wbe0,y1,wl1,statsf);
  hipLaunchKernelGGL(k_l2,dim3(PP/256),dim3(256),0,stream,y1,wl1,w2,wt2,statsf,g1,be1,wg1,wbe1,y2,wl2,statsf);
  hipLaunchKernelGGL(k_agglin,dim3(512),dim3(256),0,stream,y2,wl2,statsf,g2,be2,wg2,wbe2,lwbf,lin,statsf+2*ST_LIN);
  hipLaunchKernelGGL(k_out,dim3(1024),dim3(256),0,stream,lin,statsf,lg,lbe,out+BB*3*SS);
}